// Round 1
// baseline (296.503 us; speedup 1.0000x reference)
//
#include <hip/hip_runtime.h>
#include <cmath>

// SSIM over (32,3,512,512) f32 pairs, 11x11 separable gaussian, valid conv,
// scalar mean output. Round 6: same geometry as R5 (32x64 strips, 74-row f4
// h-buffer, bit-swapped conflict-free Phase-A map, 8 rows/thread Phase B),
// plus a manual 2/3-deep software pipeline in Phase A: each thread issues the
// global loads for its NEXT task before computing the current one, so the
// ~900-cycle cold-HBM latency of task t+1 hides under task t's ~480 cycles of
// FMA work. R5 counters showed VGPR=52 (no compiler pipelining), VALUBusy=43%,
// occupancy 30% -> latency-bound, not BW (15% HBM) or issue-bound.
// Peak regs ~= 2x32 payload + 16 accum + addr < 128 cap, occupancy unchanged.

#define HH 512
#define WW 512
#define OH 502           // 512 - 11 + 1
#define OW 502
#define NC 96            // 32 * 3
#define TXS 32           // strip width (output cols)
#define TYB 64           // band height (output rows)
#define INR 74           // h-buffer rows = TYB + 10
#define HP4 33           // row stride in float4s (528 B -> 4-bank row rotation)
#define GX 16
#define GY 8
#define NTASK (INR * 8)  // 592 Phase-A tasks (4 h-cols each)
#define NSLOT 64         // f64 accumulator slots, 64 B apart

typedef float f4 __attribute__((ext_vector_type(4)));

struct GaussW { float g[11]; };

static __device__ __forceinline__ f4 sp(float s) { return (f4){s, s, s, s}; }

__global__ __launch_bounds__(256, 4) void ssim_kernel(
        const float* __restrict__ X, const float* __restrict__ Y,
        double* __restrict__ acc, GaussW gw) {
    // hS[r][c] = f4(conv_h(x), conv_h(y), conv_h(x^2+y^2), conv_h(x*y)), raw
    // domain. 74*33*16 = 39072 B -> 4 blocks/CU.
    __shared__ f4 hS[INR][HP4];
    __shared__ double wsum[4];

    const int tid = threadIdx.x;
    const int R0 = blockIdx.y * TYB;
    const int C0 = blockIdx.x * TXS;
    const float* Xp = X + (size_t)blockIdx.z * (HH * WW);
    const float* Yp = Y + (size_t)blockIdx.z * (HH * WW);
    const bool edge = (blockIdx.x == GX - 1);    // reads would pass col 511

    // Task map puts row in the LOW 3 bits: an 8-lane LDS service phase sees 8
    // different rows -> write banks 4*(r+q) disjoint -> conflict-free.
    auto dec = [&](int t, int& r, int& cg) {
        if (t < 576) { r = (t & 7) | ((t >> 6) << 3); cg = (t >> 3) & 7; }
        else         { int tt = t - 576; r = 72 + (tt & 1); cg = (tt >> 1) & 7; }
    };

    // Issue the 8 float4 loads for one task (payload = 32 VGPRs).
    auto ldt = [&](int r, int cg, float (&xv)[16], float (&yv)[16]) {
        const int gr = min(R0 + r, HH - 1);      // clamp feeds masked rows only
        const float* xrow = Xp + gr * WW;
        const float* yrow = Yp + gr * WW;
        const int gc = C0 + 4 * cg;              // f4-aligned
        if (!edge) {
            const float4* x4 = (const float4*)(xrow + gc);
            const float4* y4 = (const float4*)(yrow + gc);
            float4 a0 = x4[0], a1 = x4[1], a2 = x4[2], a3 = x4[3];
            float4 b0 = y4[0], b1 = y4[1], b2 = y4[2], b3 = y4[3];
            xv[0]=a0.x; xv[1]=a0.y; xv[2]=a0.z; xv[3]=a0.w;
            xv[4]=a1.x; xv[5]=a1.y; xv[6]=a1.z; xv[7]=a1.w;
            xv[8]=a2.x; xv[9]=a2.y; xv[10]=a2.z; xv[11]=a2.w;
            xv[12]=a3.x; xv[13]=a3.y; xv[14]=a3.z; xv[15]=a3.w;
            yv[0]=b0.x; yv[1]=b0.y; yv[2]=b0.z; yv[3]=b0.w;
            yv[4]=b1.x; yv[5]=b1.y; yv[6]=b1.z; yv[7]=b1.w;
            yv[8]=b2.x; yv[9]=b2.y; yv[10]=b2.z; yv[11]=b2.w;
            yv[12]=b3.x; yv[13]=b3.y; yv[14]=b3.z; yv[15]=b3.w;
        } else {
            #pragma unroll
            for (int i = 0; i < 16; ++i) {       // clamped cols feed masked
                int c = min(gc + i, WW - 1);     // outputs only (c >= 502)
                xv[i] = xrow[c];
                yv[i] = yrow[c];
            }
        }
    };

    // Horizontal 11-tap conv on one task's payload + conflict-free b128 store.
    auto cst = [&](int r, int cg, float (&xv)[16], float (&yv)[16]) {
        f4 a0v = sp(0.f), a1v = sp(0.f), a2v = sp(0.f), a3v = sp(0.f);
        #pragma unroll
        for (int k = 0; k < 14; ++k) {
            float x = xv[k], y = yv[k];
            f4 P;
            P.x = x; P.y = y;
            P.z = fmaf(x, x, y * y);             // raw domain (sum(g)=1 lets
            P.w = x * y;                         // normalization fold into epi)
            #pragma unroll
            for (int j = 0; j < 4; ++j) {
                int u = k - j;
                if (u >= 0 && u < 11) {          // statically resolved
                    f4 G = sp(gw.g[u]);
                    if (j == 0) a0v = __builtin_elementwise_fma(G, P, a0v);
                    if (j == 1) a1v = __builtin_elementwise_fma(G, P, a1v);
                    if (j == 2) a2v = __builtin_elementwise_fma(G, P, a2v);
                    if (j == 3) a3v = __builtin_elementwise_fma(G, P, a3v);
                }
            }
        }
        hS[r][4 * cg + 0] = a0v;
        hS[r][4 * cg + 1] = a1v;
        hS[r][4 * cg + 2] = a2v;
        hS[r][4 * cg + 3] = a3v;
    };

    // ---- Phase A, software-pipelined. 592 tasks / 256 threads: every thread
    // owns t0=tid and t1=tid+256; threads 0..79 also own t2=tid+512.
    // Schedule: issue(t0), issue(t1), compute(t0), issue(t2), compute(t1),
    // compute(t2) -- each load batch's latency hides under the previous
    // task's FMA chain; the compiler's counted vmcnt does the rest.
    {
        float xa[16], ya[16], xb[16], yb[16];
        int r0, g0, r1, g1;
        dec(tid, r0, g0);
        ldt(r0, g0, xa, ya);
        dec(tid + 256, r1, g1);                  // tid+256 < 592 always
        ldt(r1, g1, xb, yb);
        cst(r0, g0, xa, ya);
        const bool has2 = (tid < NTASK - 512);   // tid < 80
        int r2 = 0, g2 = 0;
        if (has2) {
            dec(tid + 512, r2, g2);
            ldt(r2, g2, xa, ya);                 // reuse t0's payload regs
        }
        cst(r1, g1, xb, yb);
        if (has2) cst(r2, g2, xa, ya);
    }
    __syncthreads();

    // ---- Phase B: vertical 11-tap conv + SSIM. 256 threads, 1 col x 8 rows.
    // Read: 8-lane phase shares a row, cols 0..7(+8m) -> banks 4(R+c) disjoint.
    const int c  = tid & 31;
    const int rb = (tid >> 5) * 8;               // 0,8,...,56
    f4 A[8];
    #pragma unroll
    for (int j = 0; j < 8; ++j) A[j] = sp(0.f);
    #pragma unroll
    for (int k = 0; k < 18; ++k) {               // rows rb..rb+17 feed rb..rb+7
        f4 v = hS[rb + k][c];                    // one ds_read_b128 per tap-row
        #pragma unroll
        for (int j = 0; j < 8; ++j) {
            int u = k - j;
            if (u >= 0 && u < 11) {
                f4 G = sp(gw.g[u]);
                A[j] = __builtin_elementwise_fma(G, v, A[j]);
            }
        }
    }

    // Epilogue: raw-domain fixup. With u=(x+1)/2: 2*mu = cx+1,
    // sigma1^2+sigma2^2 = (cs - cx^2 - cy^2)/4, sigma12 = (cp - cx*cy)/4.
    const float C1 = 1.0e-4f;
    const float C2 = 9.0e-4f;
    float nn[8], dd[8];
    #pragma unroll
    for (int j = 0; j < 8; ++j) {
        f4 v = A[j];
        float t1 = v.x + 1.f, t2 = v.y + 1.f;    // 2*mu1, 2*mu2
        float num1 = fmaf(t1 * t2, 0.5f, C1);    // 2*mu1*mu2 + C1
        float den1 = fmaf(fmaf(t2, t2, t1 * t1), 0.25f, C1);
        float num2 = fmaf(v.w - v.x * v.y, 0.5f, C2);   // 2*sigma12 + C2
        float den2 = fmaf(v.z - fmaf(v.x, v.x, v.y * v.y), 0.25f, C2);
        bool valid = (R0 + rb + j < OH) & (C0 + c < OW);
        nn[j] = valid ? num1 * num2 : 0.f;
        dd[j] = valid ? den1 * den2 : 1.f;
    }
    // 2 divides for 8 outputs: common denominator per group of 4
    // (dd >= C1*C2 ~ 1e-7; 4-products >= ~6e-29 stay normal in f32)
    double tsum = 0.0;
    #pragma unroll
    for (int g = 0; g < 8; g += 4) {
        float d01 = dd[g] * dd[g + 1], d23 = dd[g + 2] * dd[g + 3];
        float s01 = fmaf(nn[g], dd[g + 1], nn[g + 1] * dd[g]);
        float s23 = fmaf(nn[g + 2], dd[g + 3], nn[g + 3] * dd[g + 2]);
        tsum += (double)(fmaf(s01, d23, s23 * d01) / (d01 * d23));
    }

    // block reduction (double) + one f64 atomic into a strided slot
    #pragma unroll
    for (int off = 32; off > 0; off >>= 1)
        tsum += __shfl_down(tsum, off, 64);
    if ((tid & 63) == 0) wsum[tid >> 6] = tsum;
    __syncthreads();
    if (tid == 0) {
        int slot = (blockIdx.x + blockIdx.y * GX + blockIdx.z * GX * GY) & (NSLOT - 1);
        atomicAdd(&acc[slot * 8], wsum[0] + wsum[1] + wsum[2] + wsum[3]);
    }
}

__global__ void ssim_finalize(const double* __restrict__ acc,
                              float* __restrict__ out) {
    int lane = threadIdx.x;                      // 64 threads, one slot each
    double t = acc[lane * 8];
    #pragma unroll
    for (int off = 32; off > 0; off >>= 1)
        t += __shfl_down(t, off, 64);
    if (lane == 0)
        out[0] = (float)(t * (1.0 / (double)((long long)NC * OH * OW)));
}

extern "C" void kernel_launch(void* const* d_in, const int* in_sizes, int n_in,
                              void* d_out, int out_size, void* d_ws, size_t ws_size,
                              hipStream_t stream) {
    const float* X = (const float*)d_in[0];
    const float* Y = (const float*)d_in[1];
    float* out = (float*)d_out;
    double* acc = (double*)d_ws;                 // 64 slots x 64 B = 4 KB

    // d_ws is re-poisoned to 0xAA before every timed launch: zero the slots.
    hipMemsetAsync(d_ws, 0, NSLOT * 64, stream);

    // Gaussian weights (win=11, sigma=1.5), computed in f64, passed by value.
    GaussW gw;
    {
        double g[11], s = 0.0;
        for (int i = 0; i < 11; ++i) {
            double d = (double)(i - 5);
            g[i] = exp(-d * d / (2.0 * 1.5 * 1.5));
            s += g[i];
        }
        for (int i = 0; i < 11; ++i) gw.g[i] = (float)(g[i] / s);
    }

    dim3 grid(GX, GY, NC);
    ssim_kernel<<<grid, dim3(256), 0, stream>>>(X, Y, acc, gw);
    ssim_finalize<<<1, dim3(64), 0, stream>>>(acc, out);
}

// Round 2
// 296.300 us; speedup vs baseline: 1.0007x; 1.0007x over previous
//
#include <hip/hip_runtime.h>
#include <cmath>

// SSIM over (32,3,512,512) f32 pairs, 11x11 separable gaussian, valid conv,
// scalar mean output. Round 7: R6's 2/3-deep Phase-A software pipeline, now
// PINNED with __builtin_amdgcn_sched_barrier(0). R6 failed (VGPR 60 not ~110,
// dur 168us): the MachineScheduler re-sank ldt(t1)'s loads to just before
// cst(t1), collapsing the pipeline. The sched_barrier fences stop any code
// motion across them, so both tasks' 8x global_load_dwordx4 stay issued ahead
// of the first FMA chain; first use of t0 waits only to vmcnt(8) and t1's
// latency hides under t0's ~500-cycle compute. Semantic no-op vs R5/R6.

#define HH 512
#define WW 512
#define OH 502           // 512 - 11 + 1
#define OW 502
#define NC 96            // 32 * 3
#define TXS 32           // strip width (output cols)
#define TYB 64           // band height (output rows)
#define INR 74           // h-buffer rows = TYB + 10
#define HP4 33           // row stride in float4s (528 B -> 4-bank row rotation)
#define GX 16
#define GY 8
#define NTASK (INR * 8)  // 592 Phase-A tasks (4 h-cols each)
#define NSLOT 64         // f64 accumulator slots, 64 B apart

typedef float f4 __attribute__((ext_vector_type(4)));

struct GaussW { float g[11]; };

static __device__ __forceinline__ f4 sp(float s) { return (f4){s, s, s, s}; }

__global__ __launch_bounds__(256, 4) void ssim_kernel(
        const float* __restrict__ X, const float* __restrict__ Y,
        double* __restrict__ acc, GaussW gw) {
    // hS[r][c] = f4(conv_h(x), conv_h(y), conv_h(x^2+y^2), conv_h(x*y)), raw
    // domain. 74*33*16 = 39072 B -> 4 blocks/CU.
    __shared__ f4 hS[INR][HP4];
    __shared__ double wsum[4];

    const int tid = threadIdx.x;
    const int R0 = blockIdx.y * TYB;
    const int C0 = blockIdx.x * TXS;
    const float* Xp = X + (size_t)blockIdx.z * (HH * WW);
    const float* Yp = Y + (size_t)blockIdx.z * (HH * WW);
    const bool edge = (blockIdx.x == GX - 1);    // reads would pass col 511

    // Task map puts row in the LOW 3 bits: an 8-lane LDS service phase sees 8
    // different rows -> write banks 4*(r+q) disjoint -> conflict-free.
    auto dec = [&](int t, int& r, int& cg) {
        if (t < 576) { r = (t & 7) | ((t >> 6) << 3); cg = (t >> 3) & 7; }
        else         { int tt = t - 576; r = 72 + (tt & 1); cg = (tt >> 1) & 7; }
    };

    // Issue the 8 float4 loads for one task (payload = 32 VGPRs).
    auto ldt = [&](int r, int cg, float (&xv)[16], float (&yv)[16]) {
        const int gr = min(R0 + r, HH - 1);      // clamp feeds masked rows only
        const float* xrow = Xp + gr * WW;
        const float* yrow = Yp + gr * WW;
        const int gc = C0 + 4 * cg;              // f4-aligned
        if (!edge) {
            const float4* x4 = (const float4*)(xrow + gc);
            const float4* y4 = (const float4*)(yrow + gc);
            float4 a0 = x4[0], a1 = x4[1], a2 = x4[2], a3 = x4[3];
            float4 b0 = y4[0], b1 = y4[1], b2 = y4[2], b3 = y4[3];
            xv[0]=a0.x; xv[1]=a0.y; xv[2]=a0.z; xv[3]=a0.w;
            xv[4]=a1.x; xv[5]=a1.y; xv[6]=a1.z; xv[7]=a1.w;
            xv[8]=a2.x; xv[9]=a2.y; xv[10]=a2.z; xv[11]=a2.w;
            xv[12]=a3.x; xv[13]=a3.y; xv[14]=a3.z; xv[15]=a3.w;
            yv[0]=b0.x; yv[1]=b0.y; yv[2]=b0.z; yv[3]=b0.w;
            yv[4]=b1.x; yv[5]=b1.y; yv[6]=b1.z; yv[7]=b1.w;
            yv[8]=b2.x; yv[9]=b2.y; yv[10]=b2.z; yv[11]=b2.w;
            yv[12]=b3.x; yv[13]=b3.y; yv[14]=b3.z; yv[15]=b3.w;
        } else {
            #pragma unroll
            for (int i = 0; i < 16; ++i) {       // clamped cols feed masked
                int c = min(gc + i, WW - 1);     // outputs only (c >= 502)
                xv[i] = xrow[c];
                yv[i] = yrow[c];
            }
        }
    };

    // Horizontal 11-tap conv on one task's payload + conflict-free b128 store.
    auto cst = [&](int r, int cg, float (&xv)[16], float (&yv)[16]) {
        f4 a0v = sp(0.f), a1v = sp(0.f), a2v = sp(0.f), a3v = sp(0.f);
        #pragma unroll
        for (int k = 0; k < 14; ++k) {
            float x = xv[k], y = yv[k];
            f4 P;
            P.x = x; P.y = y;
            P.z = fmaf(x, x, y * y);             // raw domain (sum(g)=1 lets
            P.w = x * y;                         // normalization fold into epi)
            #pragma unroll
            for (int j = 0; j < 4; ++j) {
                int u = k - j;
                if (u >= 0 && u < 11) {          // statically resolved
                    f4 G = sp(gw.g[u]);
                    if (j == 0) a0v = __builtin_elementwise_fma(G, P, a0v);
                    if (j == 1) a1v = __builtin_elementwise_fma(G, P, a1v);
                    if (j == 2) a2v = __builtin_elementwise_fma(G, P, a2v);
                    if (j == 3) a3v = __builtin_elementwise_fma(G, P, a3v);
                }
            }
        }
        hS[r][4 * cg + 0] = a0v;
        hS[r][4 * cg + 1] = a1v;
        hS[r][4 * cg + 2] = a2v;
        hS[r][4 * cg + 3] = a3v;
    };

    // ---- Phase A, software-pipelined with PINNED schedule. 592 tasks / 256
    // threads: every thread owns t0=tid and t1=tid+256; threads 0..79 also
    // own t2=tid+512. sched_barrier(0) fences stop the MachineScheduler from
    // sinking the prefetch loads back to their uses (R6 failure mode).
    {
        float xa[16], ya[16], xb[16], yb[16];
        int r0, g0, r1, g1;
        dec(tid, r0, g0);
        ldt(r0, g0, xa, ya);                     // issue t0 loads
        dec(tid + 256, r1, g1);                  // tid+256 < 592 always
        ldt(r1, g1, xb, yb);                     // issue t1 loads
        __builtin_amdgcn_sched_barrier(0);       // -- fence: loads stay above
        cst(r0, g0, xa, ya);                     // compute t0 (t1 in flight)
        const bool has2 = (tid < NTASK - 512);   // tid < 80
        int r2 = 0, g2 = 0;
        if (has2) {
            dec(tid + 512, r2, g2);
            ldt(r2, g2, xa, ya);                 // issue t2 (reuse t0 regs)
        }
        __builtin_amdgcn_sched_barrier(0);       // -- fence: t2 loads above
        cst(r1, g1, xb, yb);                     // compute t1 (t2 in flight)
        if (has2) cst(r2, g2, xa, ya);
    }
    __syncthreads();

    // ---- Phase B: vertical 11-tap conv + SSIM. 256 threads, 1 col x 8 rows.
    // Read: 8-lane phase shares a row, cols 0..7(+8m) -> banks 4(R+c) disjoint.
    const int c  = tid & 31;
    const int rb = (tid >> 5) * 8;               // 0,8,...,56
    f4 A[8];
    #pragma unroll
    for (int j = 0; j < 8; ++j) A[j] = sp(0.f);
    #pragma unroll
    for (int k = 0; k < 18; ++k) {               // rows rb..rb+17 feed rb..rb+7
        f4 v = hS[rb + k][c];                    // one ds_read_b128 per tap-row
        #pragma unroll
        for (int j = 0; j < 8; ++j) {
            int u = k - j;
            if (u >= 0 && u < 11) {
                f4 G = sp(gw.g[u]);
                A[j] = __builtin_elementwise_fma(G, v, A[j]);
            }
        }
    }

    // Epilogue: raw-domain fixup. With u=(x+1)/2: 2*mu = cx+1,
    // sigma1^2+sigma2^2 = (cs - cx^2 - cy^2)/4, sigma12 = (cp - cx*cy)/4.
    const float C1 = 1.0e-4f;
    const float C2 = 9.0e-4f;
    float nn[8], dd[8];
    #pragma unroll
    for (int j = 0; j < 8; ++j) {
        f4 v = A[j];
        float t1 = v.x + 1.f, t2 = v.y + 1.f;    // 2*mu1, 2*mu2
        float num1 = fmaf(t1 * t2, 0.5f, C1);    // 2*mu1*mu2 + C1
        float den1 = fmaf(fmaf(t2, t2, t1 * t1), 0.25f, C1);
        float num2 = fmaf(v.w - v.x * v.y, 0.5f, C2);   // 2*sigma12 + C2
        float den2 = fmaf(v.z - fmaf(v.x, v.x, v.y * v.y), 0.25f, C2);
        bool valid = (R0 + rb + j < OH) & (C0 + c < OW);
        nn[j] = valid ? num1 * num2 : 0.f;
        dd[j] = valid ? den1 * den2 : 1.f;
    }
    // 2 divides for 8 outputs: common denominator per group of 4
    // (dd >= C1*C2 ~ 1e-7; 4-products >= ~6e-29 stay normal in f32)
    double tsum = 0.0;
    #pragma unroll
    for (int g = 0; g < 8; g += 4) {
        float d01 = dd[g] * dd[g + 1], d23 = dd[g + 2] * dd[g + 3];
        float s01 = fmaf(nn[g], dd[g + 1], nn[g + 1] * dd[g]);
        float s23 = fmaf(nn[g + 2], dd[g + 3], nn[g + 3] * dd[g + 2]);
        tsum += (double)(fmaf(s01, d23, s23 * d01) / (d01 * d23));
    }

    // block reduction (double) + one f64 atomic into a strided slot
    #pragma unroll
    for (int off = 32; off > 0; off >>= 1)
        tsum += __shfl_down(tsum, off, 64);
    if ((tid & 63) == 0) wsum[tid >> 6] = tsum;
    __syncthreads();
    if (tid == 0) {
        int slot = (blockIdx.x + blockIdx.y * GX + blockIdx.z * GX * GY) & (NSLOT - 1);
        atomicAdd(&acc[slot * 8], wsum[0] + wsum[1] + wsum[2] + wsum[3]);
    }
}

__global__ void ssim_finalize(const double* __restrict__ acc,
                              float* __restrict__ out) {
    int lane = threadIdx.x;                      // 64 threads, one slot each
    double t = acc[lane * 8];
    #pragma unroll
    for (int off = 32; off > 0; off >>= 1)
        t += __shfl_down(t, off, 64);
    if (lane == 0)
        out[0] = (float)(t * (1.0 / (double)((long long)NC * OH * OW)));
}

extern "C" void kernel_launch(void* const* d_in, const int* in_sizes, int n_in,
                              void* d_out, int out_size, void* d_ws, size_t ws_size,
                              hipStream_t stream) {
    const float* X = (const float*)d_in[0];
    const float* Y = (const float*)d_in[1];
    float* out = (float*)d_out;
    double* acc = (double*)d_ws;                 // 64 slots x 64 B = 4 KB

    // d_ws is re-poisoned to 0xAA before every timed launch: zero the slots.
    hipMemsetAsync(d_ws, 0, NSLOT * 64, stream);

    // Gaussian weights (win=11, sigma=1.5), computed in f64, passed by value.
    GaussW gw;
    {
        double g[11], s = 0.0;
        for (int i = 0; i < 11; ++i) {
            double d = (double)(i - 5);
            g[i] = exp(-d * d / (2.0 * 1.5 * 1.5));
            s += g[i];
        }
        for (int i = 0; i < 11; ++i) gw.g[i] = (float)(g[i] / s);
    }

    dim3 grid(GX, GY, NC);
    ssim_kernel<<<grid, dim3(256), 0, stream>>>(X, Y, acc, gw);
    ssim_finalize<<<1, dim3(64), 0, stream>>>(acc, out);
}